// Round 16
// baseline (124.686 us; speedup 1.0000x reference)
//
#include <hip/hip_runtime.h>
#include <math.h>

typedef _Float16 f16x8 __attribute__((ext_vector_type(8)));
typedef float f32x4 __attribute__((ext_vector_type(4)));

// ---------------------------------------------------------------------------
// MEASUREMENT ROUND 2: R11 kernels; main's proto PIPELINE repeated REP=8x
// inside one launch. Sa/Wa accumulate 8 identical passes -> out = W/S exactly
// invariant. T16 = P + o + M_pro + 8*M_loop; with R11 (=39.4) and R15
// (M_pro+M_loop = 18.55): M_loop = (T16-39.4)/7. Also lifts main above the
// 48us harness fills in the profile top-5 -> first real counters for main.
// ---------------------------------------------------------------------------
// qry (256c,16384px) f32; sup_x (5,256,128,128) f32; sup_y (5,128,128) f32.
// pred[px] = sum_m softmax(mask? d : NEG)_m * d_m, d = 20*<q_n[px], p_n[m]>.
// sum_c q_n[c] = 0 => MFMA on RAW pooled x (f16); d = alpha[m]*acc.
// Fixed-max softmax e = mk*exp(d-20). pro_raw swizzled: chunk g at g^(m&7).
// ---------------------------------------------------------------------------

__global__ __launch_bounds__(256) void pool_kernel(const float* __restrict__ sup_x,
                                                   const float* __restrict__ sup_y,
                                                   _Float16* __restrict__ pro_raw,
                                                   float* __restrict__ psum,
                                                   float* __restrict__ yv_ws) {
    const int b = blockIdx.x, t = threadIdx.x;
    if (b < 640) {
        __shared__ float hs[8192];          // 32 KB: [run 256][lane 32] h-4sums
        __shared__ float xa[16][33];        // [gx][c] pooled values, padded
        const int s = b >> 7, rem = b & 127;
        const int gy = rem >> 3, cq = rem & 7;
        const float* base = sup_x + ((size_t)(s * 256 + cq * 32) * 128 + gy * 8) * 128;
#pragma unroll 8
        for (int i = 0; i < 32; ++i) {
            const int run = i * 8 + (t >> 5);
            const float4 v = *(const float4*)(base + ((size_t)(run >> 3) * 128 + (run & 7)) * 128 + (t & 31) * 4);
            hs[i * 256 + t] = v.x + v.y + v.z + v.w;
        }
        __syncthreads();
#pragma unroll
        for (int e0 = 0; e0 < 2; ++e0) {    // entry e = (c<<4)|gx
            const int e = e0 * 256 + t;
            const int c = e >> 4, gx = e & 15;
            float sum = 0.f;
#pragma unroll
            for (int r = 0; r < 8; ++r)
                sum += hs[(c * 8 + r) * 32 + gx * 2] + hs[(c * 8 + r) * 32 + gx * 2 + 1];
            xa[gx][c] = sum * (1.f / 64.f);
        }
        __syncthreads();
        const int mbase = s * 256 + gy * 16;
        if (t < 64) {                        // write 16m x 4 chunks f16 swizzled
            const int gx = t >> 2, gi = t & 3;
            const int m = mbase + gx;
            const int g = cq * 4 + gi;
            f16x8 hv;
#pragma unroll
            for (int j = 0; j < 8; ++j) hv[j] = (_Float16)xa[gx][gi * 8 + j];
            *(f16x8*)(pro_raw + (size_t)m * 256 + ((g ^ (m & 7)) << 3)) = hv;
        } else if (t < 80) {                 // partial stats over this block's 32 c
            const int gx = t - 64;
            float s1 = 0.f, s2 = 0.f;
#pragma unroll
            for (int c = 0; c < 32; ++c) { const float x = xa[gx][c]; s1 += x; s2 += x * x; }
            const int m = mbase + gx;
            psum[m * 16 + cq * 2]     = s1;
            psum[m * 16 + cq * 2 + 1] = s2;
        }
    } else {
        const int r = b - 640;
        const int gy = t >> 4, gx = t & 15;
        const float* base = sup_y + r * 16384 + gy * 1024 + gx * 8;
        float sum = 0.f;
#pragma unroll
        for (int rr = 0; rr < 8; ++rr) {
            const float4 a = *(const float4*)(base + rr * 128);
            const float4 bb = *(const float4*)(base + rr * 128 + 4);
            sum += a.x + a.y + a.z + a.w + bb.x + bb.y + bb.z + bb.w;
        }
        yv_ws[r * 256 + t] = sum * (1.f / 64.f);
    }
}

__device__ __forceinline__ void gload_lds16h(const _Float16* g, _Float16* l) {
    __builtin_amdgcn_global_load_lds((const __attribute__((address_space(1))) unsigned int*)g,
                                     (__attribute__((address_space(3))) unsigned int*)l,
                                     16, 0, 0);
}
__device__ __forceinline__ void gload_lds16f(const float* g, float* l) {
    __builtin_amdgcn_global_load_lds((const __attribute__((address_space(1))) unsigned int*)g,
                                     (__attribute__((address_space(3))) unsigned int*)l,
                                     16, 0, 0);
}

__device__ __forceinline__ void stage_tile(const _Float16* __restrict__ pro_raw,
                                           int tile, _Float16* dst, int w, int l) {
#pragma unroll
    for (int i = 0; i < 8; ++i) {
        const int off = w * 4096 + i * 512 + l * 8;
        gload_lds16h(pro_raw + (size_t)tile * 32768 + off, dst + off);
    }
}

__device__ __forceinline__ void compute_tile(const _Float16* __restrict__ pb,
                                             const float* __restrict__ msp,
                                             const float* __restrict__ asp,
                                             const f16x8 (&bfr)[4][8],
                                             int row, int ln7, int lq,
                                             float (&Sa)[4], float (&Wa)[4]) {
    f32x4 acc[4];
#pragma unroll
    for (int p = 0; p < 4; ++p) acc[p] = (f32x4){0.f, 0.f, 0.f, 0.f};
#pragma unroll
    for (int ks = 0; ks < 8; ++ks) {
        const int ch = (ks * 4 + lq) ^ ln7;
        const f16x8 a = *(const f16x8*)(pb + row * 256 + ch * 8);
#pragma unroll
        for (int p = 0; p < 4; ++p)
            acc[p] = __builtin_amdgcn_mfma_f32_16x16x32_f16(a, bfr[p][ks], acc[p], 0, 0, 0);
    }
    const f32x4 mkv = *(const f32x4*)(msp + lq * 4);
    const f32x4 av  = *(const f32x4*)(asp + lq * 4);
#pragma unroll
    for (int p = 0; p < 4; ++p) {
        float ssum = 0.f, wsum = 0.f;
#pragma unroll
        for (int r = 0; r < 4; ++r) {
            const float d = av[r] * acc[p][r];
            const float e = mkv[r] * __expf(d - 20.f);
            ssum += e; wsum += e * d;
        }
        Sa[p] += ssum; Wa[p] += wsum;
    }
}

__global__ __launch_bounds__(512, 2) void main_kernel(const float* __restrict__ qry,
                                                      const _Float16* __restrict__ pro_raw,
                                                      const float* __restrict__ psum,
                                                      const float* __restrict__ yv_ws,
                                                      float* __restrict__ out) {
    __shared__ __align__(16) _Float16 arena[65536];   // 128 KB
    __shared__ float ms[1280];
    __shared__ float alf[1280];
    __shared__ float scr[1024];
    __shared__ float2 stats[64];
    __shared__ int iflags[2];

    float*     qtf  = (float*)arena;        // 64 KB [c][64px] (prologue)
    _Float16*  qs   = arena + 32768;        // bytes [64K,96K) (prologue)
    _Float16*  buf0 = arena;                // bytes [0,64K)   (main)
    _Float16*  buf1 = arena + 32768;        // bytes [64K,128K)(main)
    float*     red  = (float*)arena;        // 16 KB (epilogue, overlays buf0)

    const int t = threadIdx.x;
    const int w = t >> 6, l = t & 63;
    const int ln = l & 15, lq = l >> 4;
    const int ln7 = ln & 7;
    const int px0 = blockIdx.x * 64;

    if (t < 2) iflags[t] = 0;
    __syncthreads();

    // ---- issue qry staging ----
#pragma unroll
    for (int i = 0; i < 8; ++i) {
        const int c = i * 32 + (t >> 4);
        gload_lds16f(qry + (size_t)c * 16384 + px0 + (t & 15) * 4,
                     qtf + i * 2048 + t * 4);
    }

    // ---- alpha[m] + mask flags ----
    float yv3[3];
    int f0 = 0, f1 = 0;
#pragma unroll
    for (int k = 0; k < 3; ++k) {
        const int m = t + k * 512;
        if (m < 1280) {
            float S1 = 0.f, S2 = 0.f;
            const f32x4* pp = (const f32x4*)(psum + m * 16);
#pragma unroll
            for (int u = 0; u < 4; ++u) {
                const f32x4 p = pp[u];
                S1 += p[0] + p[2]; S2 += p[1] + p[3];
            }
            alf[m] = 20.f / fmaxf(sqrtf(fmaxf(S2 - S1 * S1 * (1.f / 256.f), 0.f)), 1e-4f);
            const float y = yv_ws[m];
            yv3[k] = y;
            if (y > 0.5f) f0 = 1;
            if (y > 0.1f) f1 = 1;
        }
    }
    if (f0) atomicOr(&iflags[0], 1);
    if (f1) atomicOr(&iflags[1], 1);
    __syncthreads();
    {
        const int mode = iflags[0] ? 0 : (iflags[1] ? 1 : 2);
#pragma unroll
        for (int k = 0; k < 3; ++k) {
            const int m = t + k * 512;
            if (m < 1280)
                ms[m] = (mode == 0) ? (yv3[k] > 0.5f ? 1.f : 0.f)
                      : (mode == 1) ? (yv3[k] > 0.1f ? 1.f : 0.f) : 1.f;
        }
    }

    // ---- qnorm ----
    {
        const int p = t & 63, q = t >> 6;
        float s1 = 0.f, s2 = 0.f;
        for (int cc = 0; cc < 32; ++cc) {
            const float x = qtf[(q * 32 + cc) * 64 + p];
            s1 += x; s2 += x * x;
        }
        scr[q * 64 + p] = s1; scr[512 + q * 64 + p] = s2;
    }
    __syncthreads();
    if (t < 64) {
        float S1 = 0.f, S2 = 0.f;
        for (int q = 0; q < 8; ++q) { S1 += scr[q * 64 + t]; S2 += scr[512 + q * 64 + t]; }
        const float mu = S1 * (1.f / 256.f);
        const float nrm = sqrtf(fmaxf(S2 - 256.f * mu * mu, 0.f));
        stats[t] = make_float2(mu, 1.f / fmaxf(nrm, 1e-4f));
    }
    __syncthreads();
    {
        const int px = t & 63, e = t >> 6;
        const float2 st = stats[px];
#pragma unroll
        for (int u = 0; u < 4; ++u) {
            const int g = e * 4 + u;
            f16x8 hv;
#pragma unroll
            for (int j = 0; j < 8; ++j)
                hv[j] = (_Float16)((qtf[(g * 8 + j) * 64 + px] - st.x) * st.y);
            *(f16x8*)(qs + px * 256 + ((g ^ (px & 7)) << 3)) = hv;
        }
    }
    __syncthreads();

    // ---- hoist B fragments ----
    f16x8 bfr[4][8];
#pragma unroll
    for (int p = 0; p < 4; ++p) {
        const int px = p * 16 + ln;
        const int sB = px & 7;
#pragma unroll
        for (int ks = 0; ks < 8; ++ks) {
            const int g = ks * 4 + lq;
            bfr[p][ks] = *(const f16x8*)(qs + px * 256 + ((g ^ sB) << 3));
        }
    }
    __syncthreads();   // all waves done reading qs -> arena free for buffers

    const int row = w * 16 + ln;
    float Sa[4] = {0.f, 0.f, 0.f, 0.f}, Wa[4] = {0.f, 0.f, 0.f, 0.f};

    // ==== MEASUREMENT: pipeline repeated REP times; S,W scale by REP ->
    // out = W/S invariant. M_loop = (T16 - 39.4)/7.
#pragma unroll 1
    for (int rep = 0; rep < 8; ++rep) {
        asm volatile("s_waitcnt lgkmcnt(0)" ::: "memory");
        __builtin_amdgcn_sched_barrier(0);
        stage_tile(pro_raw, 0, buf0, w, l);
        stage_tile(pro_raw, 1, buf1, w, l);
#pragma unroll 1
        for (int tile = 0; tile < 10; ++tile) {
            if (tile < 8) asm volatile("s_waitcnt vmcnt(8)" ::: "memory");
            else          asm volatile("s_waitcnt vmcnt(0)" ::: "memory");
            compute_tile((tile & 1) ? buf1 : buf0,
                         ms + tile * 128 + w * 16, alf + tile * 128 + w * 16,
                         bfr, row, ln7, lq, Sa, Wa);
            if (tile < 8) {
                asm volatile("s_waitcnt lgkmcnt(0)" ::: "memory");
                __builtin_amdgcn_sched_barrier(0);
                stage_tile(pro_raw, tile + 2, (tile & 1) ? buf1 : buf0, w, l);
            }
        }
    }

    __syncthreads();   // all waves done with buffers -> red overlay safe
#pragma unroll
    for (int p = 0; p < 4; ++p) {
        const int px = p * 16 + ln;
        const int slot = (w * 4 + lq + px) & 31;
        red[px * 32 + slot] = Sa[p];
        red[2048 + px * 32 + slot] = Wa[p];
    }
    __syncthreads();
    if (t < 64) {
        float S = 0.f, W = 0.f;
        for (int s = 0; s < 32; ++s) {
            const int slot = (s + t) & 31;
            S += red[t * 32 + slot];
            W += red[2048 + t * 32 + slot];
        }
        out[px0 + t] = W / S;
    }
}

extern "C" void kernel_launch(void* const* d_in, const int* in_sizes, int n_in,
                              void* d_out, int out_size, void* d_ws, size_t ws_size,
                              hipStream_t stream) {
    const float* qry   = (const float*)d_in[0];   // 256*16384
    const float* sup_x = (const float*)d_in[1];   // 5*256*16384
    const float* sup_y = (const float*)d_in[2];   // 5*16384
    float* out = (float*)d_out;                   // 16384

    char* ws = (char*)d_ws;
    _Float16*  pro_raw = (_Float16*)ws;           ws += 1280 * 256 * 2;   // 640 KB
    float*     psum    = (float*)ws;              ws += 1280 * 16 * 4;    // 80 KB
    float*     yv_ws   = (float*)ws;              /* 5 KB */

    pool_kernel<<<645, 256, 0, stream>>>(sup_x, sup_y, pro_raw, psum, yv_ws);
    main_kernel<<<256, 512, 0, stream>>>(qry, pro_raw, psum, yv_ws, out);
}

// Round 17
// 44.321 us; speedup vs baseline: 2.8133x; 2.8133x over previous
//
#include <hip/hip_runtime.h>
#include <math.h>

typedef _Float16 f16x8 __attribute__((ext_vector_type(8)));
typedef float f32x4 __attribute__((ext_vector_type(4)));

// ---------------------------------------------------------------------------
// qry (256c,16384px) f32; sup_x (5,256,128,128) f32; sup_y (5,128,128) f32.
// pred[px] = sum_m softmax(mask? d : NEG)_m * d_m, d = 20*<q_n[px], p_n[m]>.
// FULL rank-1 identity (both operands raw):
//   d = (acc_raw - 256*muq*mup) * 20/(nuq*nup)
//     = acc*am[m]*aq[px] - cm[m]*cq[px]
//   am = 20/nup, cm = 20*mup/nup, aq = 1/nuq, cq = 256*muq/nuq  (nu clamped 1e-4)
// Softmax fixed-max in exp2 domain: e = exp2(d*log2e + B[m]),
//   B = mask ? -20*log2e : -1e30  (masked -> e = 0 exactly).
// pro_raw PRE-SWIZZLED: row m, 16B chunk g at g^(m&7); qs same per px row.
// R16 counters: loop was occupancy-bound (1 blk/CU, 21%). This version: LDS
// ~79KB -> 2 blocks/CU, 64m tiles, 2-barrier/tile pipeline, counted vmcnt(4).
// ---------------------------------------------------------------------------

__global__ __launch_bounds__(256) void pool_kernel(const float* __restrict__ sup_x,
                                                   const float* __restrict__ sup_y,
                                                   _Float16* __restrict__ pro_raw,
                                                   float* __restrict__ psum,
                                                   float* __restrict__ yv_ws) {
    const int b = blockIdx.x, t = threadIdx.x;
    if (b < 640) {
        __shared__ float hs[8192];          // 32 KB: [run 256][lane 32] h-4sums
        __shared__ float xa[16][33];        // [gx][c] pooled values, padded
        const int s = b >> 7, rem = b & 127;
        const int gy = rem >> 3, cq = rem & 7;
        const float* base = sup_x + ((size_t)(s * 256 + cq * 32) * 128 + gy * 8) * 128;
#pragma unroll 8
        for (int i = 0; i < 32; ++i) {
            const int run = i * 8 + (t >> 5);
            const float4 v = *(const float4*)(base + ((size_t)(run >> 3) * 128 + (run & 7)) * 128 + (t & 31) * 4);
            hs[i * 256 + t] = v.x + v.y + v.z + v.w;
        }
        __syncthreads();
#pragma unroll
        for (int e0 = 0; e0 < 2; ++e0) {
            const int e = e0 * 256 + t;
            const int c = e >> 4, gx = e & 15;
            float sum = 0.f;
#pragma unroll
            for (int r = 0; r < 8; ++r)
                sum += hs[(c * 8 + r) * 32 + gx * 2] + hs[(c * 8 + r) * 32 + gx * 2 + 1];
            xa[gx][c] = sum * (1.f / 64.f);
        }
        __syncthreads();
        const int mbase = s * 256 + gy * 16;
        if (t < 64) {
            const int gx = t >> 2, gi = t & 3;
            const int m = mbase + gx;
            const int g = cq * 4 + gi;
            f16x8 hv;
#pragma unroll
            for (int j = 0; j < 8; ++j) hv[j] = (_Float16)xa[gx][gi * 8 + j];
            *(f16x8*)(pro_raw + (size_t)m * 256 + ((g ^ (m & 7)) << 3)) = hv;
        } else if (t < 80) {
            const int gx = t - 64;
            float s1 = 0.f, s2 = 0.f;
#pragma unroll
            for (int c = 0; c < 32; ++c) { const float x = xa[gx][c]; s1 += x; s2 += x * x; }
            const int m = mbase + gx;
            psum[m * 16 + cq * 2]     = s1;
            psum[m * 16 + cq * 2 + 1] = s2;
        }
    } else {
        const int r = b - 640;
        const int gy = t >> 4, gx = t & 15;
        const float* base = sup_y + r * 16384 + gy * 1024 + gx * 8;
        float sum = 0.f;
#pragma unroll
        for (int rr = 0; rr < 8; ++rr) {
            const float4 a = *(const float4*)(base + rr * 128);
            const float4 bb = *(const float4*)(base + rr * 128 + 4);
            sum += a.x + a.y + a.z + a.w + bb.x + bb.y + bb.z + bb.w;
        }
        yv_ws[r * 256 + t] = sum * (1.f / 64.f);
    }
}

__device__ __forceinline__ void gload_lds16h(const _Float16* g, _Float16* l) {
    __builtin_amdgcn_global_load_lds((const __attribute__((address_space(1))) unsigned int*)g,
                                     (__attribute__((address_space(3))) unsigned int*)l,
                                     16, 0, 0);
}

// stage one 64m x 256c f16 tile (32 KB): wave w -> its 4KB slice, 4 issues
__device__ __forceinline__ void stage_tile64(const _Float16* __restrict__ pro_raw,
                                             int tile, _Float16* dst, int w, int l) {
#pragma unroll
    for (int i = 0; i < 4; ++i) {
        const int off = w * 2048 + i * 512 + l * 8;
        gload_lds16h(pro_raw + (size_t)tile * 16384 + off, dst + off);
    }
}

// K2: 256 blocks x 512 thr, 2 blocks/CU. 64 px/block, 20 tiles of 64 m.
// Wave w: px-half h=w&1, m-slice v=w>>1 (16 m). 2 barriers/tile, vmcnt(4).
__global__ __launch_bounds__(512, 4) void main_kernel(const float* __restrict__ qry,
                                                      const _Float16* __restrict__ pro_raw,
                                                      const float* __restrict__ psum,
                                                      const float* __restrict__ yv_ws,
                                                      float* __restrict__ out) {
    __shared__ __align__(16) _Float16 arena[32768];   // 64 KB: qs | buf0+buf1 | red
    __shared__ float am_s[1280], cm_s[1280], B_s[1280];  // 15 KB
    __shared__ int iflags[2];

    _Float16* qs   = arena;                   // 32 KB (prologue; = buf0 area)
    _Float16* buf0 = arena;                   // 32 KB
    _Float16* buf1 = arena + 16384;           // 32 KB
    float*    scr  = (float*)(arena + 16384); // 4 KB partials (buf1 area, prologue)
    float*    stp  = (float*)(arena + 16384) + 1024;  // stats float2[64] (buf1 area)
    float*    red  = (float*)arena;           // 8 KB (epilogue)

    const int t = threadIdx.x;
    const int w = t >> 6, l = t & 63;
    const int ln = l & 15, lq = l >> 4, ln7 = ln & 7;
    const int h = w & 1, v = w >> 1;
    const int px0 = blockIdx.x * 64;
    const float LOG2E = 1.44269504f;

    if (t < 2) iflags[t] = 0;

    // ---- prologue A: load qry (raw), per-px stats in-lane, pack f16 -> qs ----
    // wave w covers channels w*32..w*32+31 for all 64 px (lane = px).
    {
        float s1 = 0.f, s2 = 0.f;
#pragma unroll
        for (int j = 0; j < 4; ++j) {         // 4 chunks of 8 channels
            f16x8 hv;
#pragma unroll
            for (int cc = 0; cc < 8; ++cc) {
                const int c = w * 32 + j * 8 + cc;
                const float x = qry[(size_t)c * 16384 + px0 + l];
                s1 += x; s2 += x * x;
                hv[cc] = (_Float16)x;
            }
            const int g = w * 4 + j;
            *(f16x8*)(qs + l * 256 + ((g ^ (l & 7)) << 3)) = hv;
        }
        scr[w * 64 + l] = s1;
        scr[512 + w * 64 + l] = s2;
    }

    // ---- prologue B: per-m am/cm + mask flags (m = t, t+512, t+1024) ----
    float yv3[3];
    int f0 = 0, f1 = 0;
#pragma unroll
    for (int k = 0; k < 3; ++k) {
        const int m = t + k * 512;
        if (m < 1280) {
            float S1 = 0.f, S2 = 0.f;
            const f32x4* pp = (const f32x4*)(psum + m * 16);
#pragma unroll
            for (int u = 0; u < 4; ++u) {
                const f32x4 p = pp[u];
                S1 += p[0] + p[2]; S2 += p[1] + p[3];
            }
            const float mup = S1 * (1.f / 256.f);
            const float nup = fmaxf(sqrtf(fmaxf(S2 - S1 * mup, 0.f)), 1e-4f);
            am_s[m] = 20.f / nup;
            cm_s[m] = 20.f * mup / nup;
            const float y = yv_ws[m];
            yv3[k] = y;
            if (y > 0.5f) f0 = 1;
            if (y > 0.1f) f1 = 1;
        }
    }
    if (f0) atomicOr(&iflags[0], 1);
    if (f1) atomicOr(&iflags[1], 1);
    __syncthreads();

    // ---- prologue C: finalize px stats; B_s from mode ----
    if (t < 64) {
        float S1 = 0.f, S2 = 0.f;
#pragma unroll
        for (int q = 0; q < 8; ++q) { S1 += scr[q * 64 + t]; S2 += scr[512 + q * 64 + t]; }
        const float muq = S1 * (1.f / 256.f);
        const float nuq = fmaxf(sqrtf(fmaxf(S2 - S1 * muq, 0.f)), 1e-4f);
        stp[2 * t]     = 1.f / nuq;             // aq
        stp[2 * t + 1] = 256.f * muq / nuq;     // cq
    }
    {
        const int mode = iflags[0] ? 0 : (iflags[1] ? 1 : 2);
#pragma unroll
        for (int k = 0; k < 3; ++k) {
            const int m = t + k * 512;
            if (m < 1280) {
                const int mk = (mode == 0) ? (yv3[k] > 0.5f) : (mode == 1) ? (yv3[k] > 0.1f) : 1;
                B_s[m] = mk ? (-20.f * LOG2E) : -1e30f;
            }
        }
    }
    __syncthreads();

    // ---- prologue D: per-lane aq/cq + hoist B fragments from qs ----
    float aq[2], cq[2];
    f16x8 bfr[2][8];
#pragma unroll
    for (int g = 0; g < 2; ++g) {
        const int px = h * 32 + g * 16 + ln;
        aq[g] = stp[2 * px];
        cq[g] = stp[2 * px + 1];
        const int sB = px & 7;
#pragma unroll
        for (int ks = 0; ks < 8; ++ks) {
            const int gg = ks * 4 + lq;
            bfr[g][ks] = *(const f16x8*)(qs + px * 256 + ((gg ^ sB) << 3));
        }
    }
    __syncthreads();   // qs/scr/stp dead -> buffers free

    // ---- pipeline: 20 tiles of 64 m, dbuf, 2 barriers/tile, vmcnt(4) ----
    stage_tile64(pro_raw, 0, buf0, w, l);
    stage_tile64(pro_raw, 1, buf1, w, l);

    const int row = v * 16 + ln;
    float Sa[2] = {0.f, 0.f}, Wa[2] = {0.f, 0.f};

#pragma unroll 1
    for (int tile = 0; tile < 20; ++tile) {
        if (tile < 19) asm volatile("s_waitcnt vmcnt(4)" ::: "memory");
        else           asm volatile("s_waitcnt vmcnt(0)" ::: "memory");
        __builtin_amdgcn_s_barrier();         // all waves' tile loads landed
        {
            const _Float16* pb = (tile & 1) ? buf1 : buf0;
            f32x4 acc0 = {0.f, 0.f, 0.f, 0.f}, acc1 = {0.f, 0.f, 0.f, 0.f};
#pragma unroll
            for (int ks = 0; ks < 8; ++ks) {
                const int ch = (ks * 4 + lq) ^ ln7;
                const f16x8 a = *(const f16x8*)(pb + row * 256 + ch * 8);
                acc0 = __builtin_amdgcn_mfma_f32_16x16x32_f16(a, bfr[0][ks], acc0, 0, 0, 0);
                acc1 = __builtin_amdgcn_mfma_f32_16x16x32_f16(a, bfr[1][ks], acc1, 0, 0, 0);
            }
            const int mb = tile * 64 + v * 16 + lq * 4;
            const f32x4 am4 = *(const f32x4*)(am_s + mb);
            const f32x4 cm4 = *(const f32x4*)(cm_s + mb);
            const f32x4 B4  = *(const f32x4*)(B_s + mb);
#pragma unroll
            for (int g = 0; g < 2; ++g) {
                const f32x4 A = g ? acc1 : acc0;
                float ss = 0.f, ww = 0.f;
#pragma unroll
                for (int r = 0; r < 4; ++r) {
                    const float t1 = A[r] * am4[r];
                    const float d  = fmaf(t1, aq[g], -cm4[r] * cq[g]);
                    const float e  = exp2f(fmaf(d, LOG2E, B4[r]));
                    ss += e; ww = fmaf(e, d, ww);
                }
                Sa[g] += ss; Wa[g] += ww;
            }
        }
        asm volatile("s_waitcnt lgkmcnt(0)" ::: "memory");
        __builtin_amdgcn_sched_barrier(0);
        __builtin_amdgcn_s_barrier();         // all reads of this buf done
        if (tile < 18)
            stage_tile64(pro_raw, tile + 2, (tile & 1) ? buf1 : buf0, w, l);
    }

    __syncthreads();   // buffers dead -> red overlay safe
#pragma unroll
    for (int g = 0; g < 2; ++g) {
        const int px = h * 32 + g * 16 + ln;
        const int slot = (v * 4 + lq + px) & 15;
        red[px * 16 + slot] = Sa[g];
        red[1024 + px * 16 + slot] = Wa[g];
    }
    __syncthreads();
    if (t < 64) {
        float S = 0.f, W = 0.f;
#pragma unroll
        for (int s = 0; s < 16; ++s) {
            const int slot = (s + t) & 15;
            S += red[t * 16 + slot];
            W += red[1024 + t * 16 + slot];
        }
        out[px0 + t] = W / S;
    }
}

extern "C" void kernel_launch(void* const* d_in, const int* in_sizes, int n_in,
                              void* d_out, int out_size, void* d_ws, size_t ws_size,
                              hipStream_t stream) {
    const float* qry   = (const float*)d_in[0];   // 256*16384
    const float* sup_x = (const float*)d_in[1];   // 5*256*16384
    const float* sup_y = (const float*)d_in[2];   // 5*16384
    float* out = (float*)d_out;                   // 16384

    char* ws = (char*)d_ws;
    _Float16*  pro_raw = (_Float16*)ws;           ws += 1280 * 256 * 2;   // 640 KB
    float*     psum    = (float*)ws;              ws += 1280 * 16 * 4;    // 80 KB
    float*     yv_ws   = (float*)ws;              /* 5 KB */

    pool_kernel<<<645, 256, 0, stream>>>(sup_x, sup_y, pro_raw, psum, yv_ws);
    main_kernel<<<256, 512, 0, stream>>>(qry, pro_raw, psum, yv_ws, out);
}

// Round 18
// 40.950 us; speedup vs baseline: 3.0448x; 1.0823x over previous
//
#include <hip/hip_runtime.h>
#include <math.h>

typedef _Float16 f16x8 __attribute__((ext_vector_type(8)));
typedef float f32x4 __attribute__((ext_vector_type(4)));

// ---------------------------------------------------------------------------
// qry (256c,16384px) f32; sup_x (5,256,128,128) f32; sup_y (5,128,128) f32.
// pred[px] = sum_m softmax(mask? d : NEG)_m * d_m, d = 20*<q_n[px], p_n[m]>.
// Rank-1 identity (verified R17, absmax unchanged): both operands RAW in MFMA;
//   d*log2e = acc*amq[m,px] - ccq[m,px] with amq = 20*log2e/(nup*nuq),
//   ccq = 20*log2e*256*mup*muq/(nup*nuq).  e = exp2(dl + B[m]),
//   B = mask ? -20*log2e : -1e30 (masked -> e = 0 exactly).
//   W accumulated as W' = sum e*dl; final W = W'/log2e.
// pro_raw PRE-SWIZZLED: row m, 16B chunk g at g^(m&7); qs same per px row.
// R15/R16 decomposition: M_pro 6.4us, M_loop 12.2us, pool+overhead 20.8us.
// R17 lesson: block-wide per-tile barriers + (512,4) VGPR cap regress; LDS
// caps per-wave-dbuf scheme at 2 waves/SIMD (16KB/wave x 8 waves = 128KB).
// ---------------------------------------------------------------------------

__global__ __launch_bounds__(256) void pool_kernel(const float* __restrict__ sup_x,
                                                   const float* __restrict__ sup_y,
                                                   _Float16* __restrict__ pro_raw,
                                                   float* __restrict__ psum,
                                                   float* __restrict__ yv_ws) {
    const int b = blockIdx.x, t = threadIdx.x;
    if (b < 640) {
        __shared__ float hs[8192];          // 32 KB: [run 256][lane 32] h-4sums
        __shared__ float xa[16][33];        // [gx][c] pooled values, padded
        const int s = b >> 7, rem = b & 127;
        const int gy = rem >> 3, cq = rem & 7;
        const float* base = sup_x + ((size_t)(s * 256 + cq * 32) * 128 + gy * 8) * 128;
#pragma unroll 8
        for (int i = 0; i < 32; ++i) {
            const int run = i * 8 + (t >> 5);
            const float4 v = *(const float4*)(base + ((size_t)(run >> 3) * 128 + (run & 7)) * 128 + (t & 31) * 4);
            hs[i * 256 + t] = v.x + v.y + v.z + v.w;
        }
        __syncthreads();
#pragma unroll
        for (int e0 = 0; e0 < 2; ++e0) {
            const int e = e0 * 256 + t;
            const int c = e >> 4, gx = e & 15;
            float sum = 0.f;
#pragma unroll
            for (int r = 0; r < 8; ++r)
                sum += hs[(c * 8 + r) * 32 + gx * 2] + hs[(c * 8 + r) * 32 + gx * 2 + 1];
            xa[gx][c] = sum * (1.f / 64.f);
        }
        __syncthreads();
        const int mbase = s * 256 + gy * 16;
        if (t < 64) {
            const int gx = t >> 2, gi = t & 3;
            const int m = mbase + gx;
            const int g = cq * 4 + gi;
            f16x8 hv;
#pragma unroll
            for (int j = 0; j < 8; ++j) hv[j] = (_Float16)xa[gx][gi * 8 + j];
            *(f16x8*)(pro_raw + (size_t)m * 256 + ((g ^ (m & 7)) << 3)) = hv;
        } else if (t < 80) {
            const int gx = t - 64;
            float s1 = 0.f, s2 = 0.f;
#pragma unroll
            for (int c = 0; c < 32; ++c) { const float x = xa[gx][c]; s1 += x; s2 += x * x; }
            const int m = mbase + gx;
            psum[m * 16 + cq * 2]     = s1;
            psum[m * 16 + cq * 2 + 1] = s2;
        }
    } else {
        const int r = b - 640;
        const int gy = t >> 4, gx = t & 15;
        const float* base = sup_y + r * 16384 + gy * 1024 + gx * 8;
        float sum = 0.f;
#pragma unroll
        for (int rr = 0; rr < 8; ++rr) {
            const float4 a = *(const float4*)(base + rr * 128);
            const float4 bb = *(const float4*)(base + rr * 128 + 4);
            sum += a.x + a.y + a.z + a.w + bb.x + bb.y + bb.z + bb.w;
        }
        yv_ws[r * 256 + t] = sum * (1.f / 64.f);
    }
}

__device__ __forceinline__ void gload_lds16h(const _Float16* g, _Float16* l) {
    __builtin_amdgcn_global_load_lds((const __attribute__((address_space(1))) unsigned int*)g,
                                     (__attribute__((address_space(3))) unsigned int*)l,
                                     16, 0, 0);
}
__device__ __forceinline__ void gload_lds16f(const float* g, float* l) {
    __builtin_amdgcn_global_load_lds((const __attribute__((address_space(1))) unsigned int*)g,
                                     (__attribute__((address_space(3))) unsigned int*)l,
                                     16, 0, 0);
}

// stage one 128m x 256c f16 tile: wave w stages ITS OWN 16 rows (8KB slice)
__device__ __forceinline__ void stage_tile(const _Float16* __restrict__ pro_raw,
                                           int tile, _Float16* dst, int w, int l) {
#pragma unroll
    for (int i = 0; i < 8; ++i) {
        const int off = w * 4096 + i * 512 + l * 8;
        gload_lds16h(pro_raw + (size_t)tile * 32768 + off, dst + off);
    }
}

// K2: 256 blocks x 512 thr (8 waves, 1 block/CU). R11 per-wave pipeline +
// rank-1 identity prologue (1 combined pass) + exp2 epilogue + setprio.
__global__ __launch_bounds__(512, 2) void main_kernel(const float* __restrict__ qry,
                                                      const _Float16* __restrict__ pro_raw,
                                                      const float* __restrict__ psum,
                                                      const float* __restrict__ yv_ws,
                                                      float* __restrict__ out) {
    __shared__ __align__(16) _Float16 arena[65536];   // 128 KB
    __shared__ float am_s[1280], cm_s[1280], B_s[1280];  // 15 KB
    __shared__ float scr[1024];
    __shared__ float stp[128];                        // aq,cq per px
    __shared__ int iflags[2];

    float*     qtf  = (float*)arena;        // 64 KB [c][64px] (prologue)
    _Float16*  qs   = arena + 32768;        // bytes [64K,96K) (prologue)
    _Float16*  buf0 = arena;                // bytes [0,64K)   (main)
    _Float16*  buf1 = arena + 32768;        // bytes [64K,128K)(main)
    float*     red  = (float*)arena;        // 16 KB (epilogue, overlays buf0)

    const int t = threadIdx.x;
    const int w = t >> 6, l = t & 63;
    const int ln = l & 15, lq = l >> 4;
    const int ln7 = ln & 7;
    const int px0 = blockIdx.x * 64;
    const float LOG2E = 1.44269504f;
    const float INVL2E = 0.69314718f;

    if (t < 2) iflags[t] = 0;
    __syncthreads();

    // ---- issue qry staging (f32, coalesced; latency hidden below) ----
#pragma unroll
    for (int i = 0; i < 8; ++i) {
        const int c = i * 32 + (t >> 4);
        gload_lds16f(qry + (size_t)c * 16384 + px0 + (t & 15) * 4,
                     qtf + i * 2048 + t * 4);
    }

    // ---- per-m am/cm + mask flags (m = t, t+512, t+1024) ----
    float yv3[3];
    int f0 = 0, f1 = 0;
#pragma unroll
    for (int k = 0; k < 3; ++k) {
        const int m = t + k * 512;
        if (m < 1280) {
            float S1 = 0.f, S2 = 0.f;
            const f32x4* pp = (const f32x4*)(psum + m * 16);
#pragma unroll
            for (int u = 0; u < 4; ++u) {
                const f32x4 p = pp[u];
                S1 += p[0] + p[2]; S2 += p[1] + p[3];
            }
            const float mup = S1 * (1.f / 256.f);
            const float nup = fmaxf(sqrtf(fmaxf(S2 - S1 * mup, 0.f)), 1e-4f);
            am_s[m] = 20.f / nup;            // d = am*acc/nuq - cm*cq_px
            cm_s[m] = 20.f * mup / nup;
            const float y = yv_ws[m];
            yv3[k] = y;
            if (y > 0.5f) f0 = 1;
            if (y > 0.1f) f1 = 1;
        }
    }
    if (f0) atomicOr(&iflags[0], 1);
    if (f1) atomicOr(&iflags[1], 1);
    __syncthreads();   // full drain: qtf ready, flags final
    {
        const int mode = iflags[0] ? 0 : (iflags[1] ? 1 : 2);
#pragma unroll
        for (int k = 0; k < 3; ++k) {
            const int m = t + k * 512;
            if (m < 1280) {
                const int mk = (mode == 0) ? (yv3[k] > 0.5f) : (mode == 1) ? (yv3[k] > 0.1f) : 1;
                B_s[m] = mk ? (-20.f * LOG2E) : -1e30f;
            }
        }
    }

    // ---- COMBINED pass: stats partials + raw f16 convert -> qs (one sweep) ----
    {
        const int px = t & 63, seg = t >> 6;       // 8 segs x 32 channels
        float s1 = 0.f, s2 = 0.f;
#pragma unroll
        for (int u = 0; u < 4; ++u) {
            f16x8 hv;
#pragma unroll
            for (int j = 0; j < 8; ++j) {
                const float x = qtf[(seg * 32 + u * 8 + j) * 64 + px];
                s1 += x; s2 += x * x;
                hv[j] = (_Float16)x;
            }
            const int g = seg * 4 + u;
            *(f16x8*)(qs + px * 256 + ((g ^ (px & 7)) << 3)) = hv;
        }
        scr[seg * 64 + px] = s1;
        scr[512 + seg * 64 + px] = s2;
    }
    __syncthreads();   // qtf dead -> buf0 region free; scr ready

    stage_tile(pro_raw, 0, buf0, w, l);   // overlaps stats finalize + hoist

    if (t < 64) {
        float S1 = 0.f, S2 = 0.f;
#pragma unroll
        for (int q = 0; q < 8; ++q) { S1 += scr[q * 64 + t]; S2 += scr[512 + q * 64 + t]; }
        const float muq = S1 * (1.f / 256.f);
        const float nuq = fmaxf(sqrtf(fmaxf(S2 - S1 * muq, 0.f)), 1e-4f);
        stp[2 * t]     = LOG2E / nuq;            // aqL (log2e folded)
        stp[2 * t + 1] = LOG2E * 256.f * muq / nuq;  // cqL
    }
    __syncthreads();   // stp ready (qs was ready at previous barrier)

    // ---- hoist B fragments + per-group aq/cq ----
    f16x8 bfr[4][8];
    float aqL[4], cqL[4];
#pragma unroll
    for (int p = 0; p < 4; ++p) {
        const int px = p * 16 + ln;
        aqL[p] = stp[2 * px];
        cqL[p] = stp[2 * px + 1];
        const int sB = px & 7;
#pragma unroll
        for (int ks = 0; ks < 8; ++ks) {
            const int g = ks * 4 + lq;
            bfr[p][ks] = *(const f16x8*)(qs + px * 256 + ((g ^ sB) << 3));
        }
    }
    __syncthreads();   // all waves done reading qs -> buf1 region free

    stage_tile(pro_raw, 1, buf1, w, l);

    const int row = w * 16 + ln;
    float Sa[4] = {0.f, 0.f, 0.f, 0.f}, Wa[4] = {0.f, 0.f, 0.f, 0.f};

#pragma unroll 1
    for (int tile = 0; tile < 10; ++tile) {
        if (tile < 8) asm volatile("s_waitcnt vmcnt(8)" ::: "memory");
        else          asm volatile("s_waitcnt vmcnt(0)" ::: "memory");
        {
            const _Float16* pb = (tile & 1) ? buf1 : buf0;
            f32x4 acc[4];
#pragma unroll
            for (int p = 0; p < 4; ++p) acc[p] = (f32x4){0.f, 0.f, 0.f, 0.f};
            __builtin_amdgcn_s_setprio(1);
#pragma unroll
            for (int ks = 0; ks < 8; ++ks) {
                const int ch = (ks * 4 + lq) ^ ln7;
                const f16x8 a = *(const f16x8*)(pb + row * 256 + ch * 8);
#pragma unroll
                for (int p = 0; p < 4; ++p)
                    acc[p] = __builtin_amdgcn_mfma_f32_16x16x32_f16(a, bfr[p][ks], acc[p], 0, 0, 0);
            }
            __builtin_amdgcn_s_setprio(0);
            const int mb = tile * 128 + w * 16 + lq * 4;
            const f32x4 am4 = *(const f32x4*)(am_s + mb);
            const f32x4 cm4 = *(const f32x4*)(cm_s + mb);
            const f32x4 B4  = *(const f32x4*)(B_s + mb);
#pragma unroll
            for (int p = 0; p < 4; ++p) {
                float ss = 0.f, ww = 0.f;
#pragma unroll
                for (int r = 0; r < 4; ++r) {
                    const float dl = fmaf(acc[p][r], am4[r] * aqL[p], -cm4[r] * cqL[p]);
                    const float e  = exp2f(dl + B4[r]);
                    ss += e; ww = fmaf(e, dl, ww);
                }
                Sa[p] += ss; Wa[p] += ww;
            }
        }
        asm volatile("s_waitcnt lgkmcnt(0)" ::: "memory");
        __builtin_amdgcn_sched_barrier(0);
        if (tile < 8)
            stage_tile(pro_raw, tile + 2, (tile & 1) ? buf1 : buf0, w, l);
    }

    __syncthreads();   // all waves done with buffers -> red overlay safe
#pragma unroll
    for (int p = 0; p < 4; ++p) {
        const int px = p * 16 + ln;
        const int slot = (w * 4 + lq + px) & 31;
        red[px * 32 + slot] = Sa[p];
        red[2048 + px * 32 + slot] = Wa[p] * INVL2E;  // undo log2e scaling
    }
    __syncthreads();
    if (t < 64) {
        float S = 0.f, W = 0.f;
        for (int s = 0; s < 32; ++s) {
            const int slot = (s + t) & 31;
            S += red[t * 32 + slot];
            W += red[2048 + t * 32 + slot];
        }
        out[px0 + t] = W / S;
    }
}

extern "C" void kernel_launch(void* const* d_in, const int* in_sizes, int n_in,
                              void* d_out, int out_size, void* d_ws, size_t ws_size,
                              hipStream_t stream) {
    const float* qry   = (const float*)d_in[0];   // 256*16384
    const float* sup_x = (const float*)d_in[1];   // 5*256*16384
    const float* sup_y = (const float*)d_in[2];   // 5*16384
    float* out = (float*)d_out;                   // 16384

    char* ws = (char*)d_ws;
    _Float16*  pro_raw = (_Float16*)ws;           ws += 1280 * 256 * 2;   // 640 KB
    float*     psum    = (float*)ws;              ws += 1280 * 16 * 4;    // 80 KB
    float*     yv_ws   = (float*)ws;              /* 5 KB */

    pool_kernel<<<645, 256, 0, stream>>>(sup_x, sup_y, pro_raw, psum, yv_ws);
    main_kernel<<<256, 512, 0, stream>>>(qry, pro_raw, psum, yv_ws, out);
}

// Round 19
// 39.421 us; speedup vs baseline: 3.1629x; 1.0388x over previous
//
#include <hip/hip_runtime.h>
#include <math.h>

typedef _Float16 f16x8 __attribute__((ext_vector_type(8)));
typedef float f32x4 __attribute__((ext_vector_type(4)));

// ---------------------------------------------------------------------------
// qry (256c,16384px) f32; sup_x (5,256,128,128) f32; sup_y (5,128,128) f32.
// M=1280 protos, C=256. out (16384) f32.
// pred[px] = sum_m softmax(mask? d : NEG)_m * d_m, d = 20*<q_n[px], p_n[m]>.
// Identity: sum_c q_n[c] = 0 => MFMA on RAW pooled x (f16); epilogue
// d = alpha[m]*acc, alpha = 20/max(||x-mu||,1e-4). Fixed-max softmax
// e = mk*exp(d-20) -> S,W are ORDER-INVARIANT pure sums over m.
// pro_raw PRE-SWIZZLED: row m, 16B chunk g at g^(m&7).
// R19: tile-sequence ROTATION (blockIdx%10). R16 counters showed the loop
// moves 164MB L2 at only 13.4 TB/s (39% of ceiling) with all 256 CUs
// streaming the SAME 640KB in lockstep -> L2-slice broadcast hotspot.
// Rotation decorrelates the per-CU address streams. Order-invariance of the
// fixed-max softmax makes this free.
// ---------------------------------------------------------------------------

__global__ __launch_bounds__(256) void pool_kernel(const float* __restrict__ sup_x,
                                                   const float* __restrict__ sup_y,
                                                   _Float16* __restrict__ pro_raw,
                                                   float* __restrict__ psum,
                                                   float* __restrict__ yv_ws) {
    const int b = blockIdx.x, t = threadIdx.x;
    if (b < 640) {
        __shared__ float hs[8192];          // 32 KB: [run 256][lane 32] h-4sums
        __shared__ float xa[16][33];        // [gx][c] pooled values, padded
        const int s = b >> 7, rem = b & 127;
        const int gy = rem >> 3, cq = rem & 7;
        const float* base = sup_x + ((size_t)(s * 256 + cq * 32) * 128 + gy * 8) * 128;
#pragma unroll 8
        for (int i = 0; i < 32; ++i) {
            const int run = i * 8 + (t >> 5);
            const float4 v = *(const float4*)(base + ((size_t)(run >> 3) * 128 + (run & 7)) * 128 + (t & 31) * 4);
            hs[i * 256 + t] = v.x + v.y + v.z + v.w;
        }
        __syncthreads();
#pragma unroll
        for (int e0 = 0; e0 < 2; ++e0) {    // entry e = (c<<4)|gx
            const int e = e0 * 256 + t;
            const int c = e >> 4, gx = e & 15;
            float sum = 0.f;
#pragma unroll
            for (int r = 0; r < 8; ++r)
                sum += hs[(c * 8 + r) * 32 + gx * 2] + hs[(c * 8 + r) * 32 + gx * 2 + 1];
            xa[gx][c] = sum * (1.f / 64.f);
        }
        __syncthreads();
        const int mbase = s * 256 + gy * 16;
        if (t < 64) {                        // write 16m x 4 chunks f16 swizzled
            const int gx = t >> 2, gi = t & 3;
            const int m = mbase + gx;
            const int g = cq * 4 + gi;
            f16x8 hv;
#pragma unroll
            for (int j = 0; j < 8; ++j) hv[j] = (_Float16)xa[gx][gi * 8 + j];
            *(f16x8*)(pro_raw + (size_t)m * 256 + ((g ^ (m & 7)) << 3)) = hv;
        } else if (t < 80) {                 // partial stats over this block's 32 c
            const int gx = t - 64;
            float s1 = 0.f, s2 = 0.f;
#pragma unroll
            for (int c = 0; c < 32; ++c) { const float x = xa[gx][c]; s1 += x; s2 += x * x; }
            const int m = mbase + gx;
            psum[m * 16 + cq * 2]     = s1;
            psum[m * 16 + cq * 2 + 1] = s2;
        }
    } else {
        const int r = b - 640;
        const int gy = t >> 4, gx = t & 15;
        const float* base = sup_y + r * 16384 + gy * 1024 + gx * 8;
        float sum = 0.f;
#pragma unroll
        for (int rr = 0; rr < 8; ++rr) {
            const float4 a = *(const float4*)(base + rr * 128);
            const float4 bb = *(const float4*)(base + rr * 128 + 4);
            sum += a.x + a.y + a.z + a.w + bb.x + bb.y + bb.z + bb.w;
        }
        yv_ws[r * 256 + t] = sum * (1.f / 64.f);
    }
}

__device__ __forceinline__ void gload_lds16h(const _Float16* g, _Float16* l) {
    __builtin_amdgcn_global_load_lds((const __attribute__((address_space(1))) unsigned int*)g,
                                     (__attribute__((address_space(3))) unsigned int*)l,
                                     16, 0, 0);
}
__device__ __forceinline__ void gload_lds16f(const float* g, float* l) {
    __builtin_amdgcn_global_load_lds((const __attribute__((address_space(1))) unsigned int*)g,
                                     (__attribute__((address_space(3))) unsigned int*)l,
                                     16, 0, 0);
}

__device__ __forceinline__ void stage_tile(const _Float16* __restrict__ pro_raw,
                                           int tile, _Float16* dst, int w, int l) {
#pragma unroll
    for (int i = 0; i < 8; ++i) {
        const int off = w * 4096 + i * 512 + l * 8;
        gload_lds16h(pro_raw + (size_t)tile * 32768 + off, dst + off);
    }
}

__device__ __forceinline__ void compute_tile(const _Float16* __restrict__ pb,
                                             const float* __restrict__ msp,
                                             const float* __restrict__ asp,
                                             const f16x8 (&bfr)[4][8],
                                             int row, int ln7, int lq,
                                             float (&Sa)[4], float (&Wa)[4]) {
    f32x4 acc[4];
#pragma unroll
    for (int p = 0; p < 4; ++p) acc[p] = (f32x4){0.f, 0.f, 0.f, 0.f};
#pragma unroll
    for (int ks = 0; ks < 8; ++ks) {
        const int ch = (ks * 4 + lq) ^ ln7;          // bank-correct swizzle
        const f16x8 a = *(const f16x8*)(pb + row * 256 + ch * 8);
#pragma unroll
        for (int p = 0; p < 4; ++p)
            acc[p] = __builtin_amdgcn_mfma_f32_16x16x32_f16(a, bfr[p][ks], acc[p], 0, 0, 0);
    }
    const f32x4 mkv = *(const f32x4*)(msp + lq * 4);
    const f32x4 av  = *(const f32x4*)(asp + lq * 4);
#pragma unroll
    for (int p = 0; p < 4; ++p) {
        float ssum = 0.f, wsum = 0.f;
#pragma unroll
        for (int r = 0; r < 4; ++r) {
            const float d = av[r] * acc[p][r];
            const float e = mkv[r] * __expf(d - 20.f);
            ssum += e; wsum += e * d;
        }
        Sa[p] += ssum; Wa[p] += wsum;
    }
}

// K2: 256 blocks x 512 thr (8 waves, 1 block/CU). R11 per-wave pipeline with
// per-block tile-sequence rotation (L2 hotspot decorrelation).
__global__ __launch_bounds__(512, 2) void main_kernel(const float* __restrict__ qry,
                                                      const _Float16* __restrict__ pro_raw,
                                                      const float* __restrict__ psum,
                                                      const float* __restrict__ yv_ws,
                                                      float* __restrict__ out) {
    __shared__ __align__(16) _Float16 arena[65536];   // 128 KB
    __shared__ float ms[1280];
    __shared__ float alf[1280];
    __shared__ float scr[1024];
    __shared__ float2 stats[64];
    __shared__ int iflags[2];

    float*     qtf  = (float*)arena;        // 64 KB [c][64px] (prologue)
    _Float16*  qs   = arena + 32768;        // bytes [64K,96K) (prologue)
    _Float16*  buf0 = arena;                // bytes [0,64K)   (main)
    _Float16*  buf1 = arena + 32768;        // bytes [64K,128K)(main)
    float*     red  = (float*)arena;        // 16 KB (epilogue, overlays buf0)

    const int t = threadIdx.x;
    const int w = t >> 6, l = t & 63;
    const int ln = l & 15, lq = l >> 4;
    const int ln7 = ln & 7;
    const int px0 = blockIdx.x * 64;
    // rotation: decorrelate per-CU L2 address streams (S/W order-invariant)
    const int rot = (int)blockIdx.x % 10;

    if (t < 2) iflags[t] = 0;
    __syncthreads();

    // ---- issue qry staging (latency hidden by alpha/mask compute below) ----
#pragma unroll
    for (int i = 0; i < 8; ++i) {
        const int c = i * 32 + (t >> 4);
        gload_lds16f(qry + (size_t)c * 16384 + px0 + (t & 15) * 4,
                     qtf + i * 2048 + t * 4);
    }

    // ---- alpha[m] from psum partials + mask flags (m = t, t+512, t+1024) ----
    float yv3[3];
    int f0 = 0, f1 = 0;
#pragma unroll
    for (int k = 0; k < 3; ++k) {
        const int m = t + k * 512;
        if (m < 1280) {
            float S1 = 0.f, S2 = 0.f;
            const f32x4* pp = (const f32x4*)(psum + m * 16);
#pragma unroll
            for (int u = 0; u < 4; ++u) {
                const f32x4 p = pp[u];
                S1 += p[0] + p[2]; S2 += p[1] + p[3];
            }
            alf[m] = 20.f / fmaxf(sqrtf(fmaxf(S2 - S1 * S1 * (1.f / 256.f), 0.f)), 1e-4f);
            const float y = yv_ws[m];
            yv3[k] = y;
            if (y > 0.5f) f0 = 1;
            if (y > 0.1f) f1 = 1;
        }
    }
    if (f0) atomicOr(&iflags[0], 1);
    if (f1) atomicOr(&iflags[1], 1);
    __syncthreads();   // full drain: qtf ready, flags final
    {
        const int mode = iflags[0] ? 0 : (iflags[1] ? 1 : 2);
#pragma unroll
        for (int k = 0; k < 3; ++k) {
            const int m = t + k * 512;
            if (m < 1280)
                ms[m] = (mode == 0) ? (yv3[k] > 0.5f ? 1.f : 0.f)
                      : (mode == 1) ? (yv3[k] > 0.1f ? 1.f : 0.f) : 1.f;
        }
    }

    // ---- qnorm: per-px stats then f16 convert into qs (swizzled) ----
    {
        const int p = t & 63, q = t >> 6;
        float s1 = 0.f, s2 = 0.f;
        for (int cc = 0; cc < 32; ++cc) {
            const float x = qtf[(q * 32 + cc) * 64 + p];
            s1 += x; s2 += x * x;
        }
        scr[q * 64 + p] = s1; scr[512 + q * 64 + p] = s2;
    }
    __syncthreads();
    if (t < 64) {
        float S1 = 0.f, S2 = 0.f;
        for (int q = 0; q < 8; ++q) { S1 += scr[q * 64 + t]; S2 += scr[512 + q * 64 + t]; }
        const float mu = S1 * (1.f / 256.f);
        const float nrm = sqrtf(fmaxf(S2 - 256.f * mu * mu, 0.f));
        stats[t] = make_float2(mu, 1.f / fmaxf(nrm, 1e-4f));
    }
    __syncthreads();
    {
        const int px = t & 63, e = t >> 6;
        const float2 st = stats[px];
#pragma unroll
        for (int u = 0; u < 4; ++u) {
            const int g = e * 4 + u;
            f16x8 hv;
#pragma unroll
            for (int j = 0; j < 8; ++j)
                hv[j] = (_Float16)((qtf[(g * 8 + j) * 64 + px] - st.x) * st.y);
            *(f16x8*)(qs + px * 256 + ((g ^ (px & 7)) << 3)) = hv;
        }
    }
    __syncthreads();   // qs ready; qtf dead -> buf0 region free

    stage_tile(pro_raw, rot, buf0, w, l);   // overlaps bfr hoist

    f16x8 bfr[4][8];
#pragma unroll
    for (int p = 0; p < 4; ++p) {
        const int px = p * 16 + ln;
        const int sB = px & 7;
#pragma unroll
        for (int ks = 0; ks < 8; ++ks) {
            const int g = ks * 4 + lq;
            bfr[p][ks] = *(const f16x8*)(qs + px * 256 + ((g ^ sB) << 3));
        }
    }
    __syncthreads();   // all waves done reading qs -> buf1 region free

    {
        int t1 = rot + 1; if (t1 >= 10) t1 -= 10;
        stage_tile(pro_raw, t1, buf1, w, l);
    }

    const int row = w * 16 + ln;
    float Sa[4] = {0.f, 0.f, 0.f, 0.f}, Wa[4] = {0.f, 0.f, 0.f, 0.f};

#pragma unroll 1
    for (int tile = 0; tile < 10; ++tile) {
        if (tile < 8) asm volatile("s_waitcnt vmcnt(8)" ::: "memory");
        else          asm volatile("s_waitcnt vmcnt(0)" ::: "memory");
        int tt = tile + rot; if (tt >= 10) tt -= 10;
        compute_tile((tile & 1) ? buf1 : buf0,
                     ms + tt * 128 + w * 16, alf + tt * 128 + w * 16,
                     bfr, row, ln7, lq, Sa, Wa);
        if (tile < 8) {
            // all ds_reads of this buffer retired before we overwrite it
            asm volatile("s_waitcnt lgkmcnt(0)" ::: "memory");
            __builtin_amdgcn_sched_barrier(0);
            int ts = tile + 2 + rot; if (ts >= 10) ts -= 10;
            stage_tile(pro_raw, ts, (tile & 1) ? buf1 : buf0, w, l);
        }
    }

    __syncthreads();   // all waves done with buffers -> red overlay safe
#pragma unroll
    for (int p = 0; p < 4; ++p) {
        const int px = p * 16 + ln;
        const int slot = (w * 4 + lq + px) & 31;
        red[px * 32 + slot] = Sa[p];
        red[2048 + px * 32 + slot] = Wa[p];
    }
    __syncthreads();
    if (t < 64) {
        float S = 0.f, W = 0.f;
        for (int s = 0; s < 32; ++s) {
            const int slot = (s + t) & 31;
            S += red[t * 32 + slot];
            W += red[2048 + t * 32 + slot];
        }
        out[px0 + t] = W / S;
    }
}

extern "C" void kernel_launch(void* const* d_in, const int* in_sizes, int n_in,
                              void* d_out, int out_size, void* d_ws, size_t ws_size,
                              hipStream_t stream) {
    const float* qry   = (const float*)d_in[0];   // 256*16384
    const float* sup_x = (const float*)d_in[1];   // 5*256*16384
    const float* sup_y = (const float*)d_in[2];   // 5*16384
    float* out = (float*)d_out;                   // 16384

    char* ws = (char*)d_ws;
    _Float16*  pro_raw = (_Float16*)ws;           ws += 1280 * 256 * 2;   // 640 KB
    float*     psum    = (float*)ws;              ws += 1280 * 16 * 4;    // 80 KB
    float*     yv_ws   = (float*)ws;              /* 5 KB */

    pool_kernel<<<645, 256, 0, stream>>>(sup_x, sup_y, pro_raw, psum, yv_ws);
    main_kernel<<<256, 512, 0, stream>>>(qry, pro_raw, psum, yv_ws, out);
}

// Round 20
// 34.766 us; speedup vs baseline: 3.5864x; 1.1339x over previous
//
#include <hip/hip_runtime.h>
#include <math.h>

typedef _Float16 f16x8 __attribute__((ext_vector_type(8)));
typedef float f32x4 __attribute__((ext_vector_type(4)));

// ---------------------------------------------------------------------------
// qry (256c,16384px) f32; sup_x (5,256,128,128) f32; sup_y (5,128,128) f32.
// M=1280 protos, C=256. out (16384) f32.
// pred[px] = sum_m softmax(mask? d : NEG)_m * d_m, d = 20*<q_n[px], p_n[m]>.
// Identity: sum_c q_n[c] = 0 => MFMA on RAW pooled x (f16); epilogue
// d = alpha[m]*acc, alpha = 20/max(||x-mu||,1e-4). Fixed-max softmax
// e = mk*exp(d-20); masked protos contribute EXACTLY 0 ->
// R20: COMPACT the active-proto set (mode 0 keeps ~640/1280) via in-LDS
// ballot prefix; loop runs ceil(NA/128) tiles instead of 10. pro_raw is now
// LINEAR; the gather-staging applies row indirection + XOR swizzle on the
// per-lane GLOBAL source address (LDS dest stays linear, read path unchanged).
// R19 lesson: tile rotation null -> no L2 hotspot; loop is latency-bound,
// so cut the work instead.
// ---------------------------------------------------------------------------

__global__ __launch_bounds__(256) void pool_kernel(const float* __restrict__ sup_x,
                                                   const float* __restrict__ sup_y,
                                                   _Float16* __restrict__ pro_raw,
                                                   float* __restrict__ psum,
                                                   float* __restrict__ yv_ws) {
    const int b = blockIdx.x, t = threadIdx.x;
    if (b < 640) {
        __shared__ float hs[8192];          // 32 KB: [run 256][lane 32] h-4sums
        __shared__ float xa[16][33];        // [gx][c] pooled values, padded
        const int s = b >> 7, rem = b & 127;
        const int gy = rem >> 3, cq = rem & 7;
        const float* base = sup_x + ((size_t)(s * 256 + cq * 32) * 128 + gy * 8) * 128;
#pragma unroll 8
        for (int i = 0; i < 32; ++i) {
            const int run = i * 8 + (t >> 5);
            const float4 v = *(const float4*)(base + ((size_t)(run >> 3) * 128 + (run & 7)) * 128 + (t & 31) * 4);
            hs[i * 256 + t] = v.x + v.y + v.z + v.w;
        }
        __syncthreads();
#pragma unroll
        for (int e0 = 0; e0 < 2; ++e0) {    // entry e = (c<<4)|gx
            const int e = e0 * 256 + t;
            const int c = e >> 4, gx = e & 15;
            float sum = 0.f;
#pragma unroll
            for (int r = 0; r < 8; ++r)
                sum += hs[(c * 8 + r) * 32 + gx * 2] + hs[(c * 8 + r) * 32 + gx * 2 + 1];
            xa[gx][c] = sum * (1.f / 64.f);
        }
        __syncthreads();
        const int mbase = s * 256 + gy * 16;
        if (t < 64) {                        // write 16m x 4 chunks f16 LINEAR
            const int gx = t >> 2, gi = t & 3;
            const int m = mbase + gx;
            const int g = cq * 4 + gi;
            f16x8 hv;
#pragma unroll
            for (int j = 0; j < 8; ++j) hv[j] = (_Float16)xa[gx][gi * 8 + j];
            *(f16x8*)(pro_raw + (size_t)m * 256 + (g << 3)) = hv;
        } else if (t < 80) {                 // partial stats over this block's 32 c
            const int gx = t - 64;
            float s1 = 0.f, s2 = 0.f;
#pragma unroll
            for (int c = 0; c < 32; ++c) { const float x = xa[gx][c]; s1 += x; s2 += x * x; }
            const int m = mbase + gx;
            psum[m * 16 + cq * 2]     = s1;
            psum[m * 16 + cq * 2 + 1] = s2;
        }
    } else {
        const int r = b - 640;
        const int gy = t >> 4, gx = t & 15;
        const float* base = sup_y + r * 16384 + gy * 1024 + gx * 8;
        float sum = 0.f;
#pragma unroll
        for (int rr = 0; rr < 8; ++rr) {
            const float4 a = *(const float4*)(base + rr * 128);
            const float4 bb = *(const float4*)(base + rr * 128 + 4);
            sum += a.x + a.y + a.z + a.w + bb.x + bb.y + bb.z + bb.w;
        }
        yv_ws[r * 256 + t] = sum * (1.f / 64.f);
    }
}

__device__ __forceinline__ void gload_lds16h(const _Float16* g, _Float16* l) {
    __builtin_amdgcn_global_load_lds((const __attribute__((address_space(1))) unsigned int*)g,
                                     (__attribute__((address_space(3))) unsigned int*)l,
                                     16, 0, 0);
}
__device__ __forceinline__ void gload_lds16f(const float* g, float* l) {
    __builtin_amdgcn_global_load_lds((const __attribute__((address_space(1))) unsigned int*)g,
                                     (__attribute__((address_space(3))) unsigned int*)l,
                                     16, 0, 0);
}

// gather-stage one compacted 128-row tile: wave w stages ITS OWN 16 rows.
// Source address carries row indirection (idxc) AND the XOR swizzle; LDS
// dest is linear (base + lane*16 as the HW requires).
__device__ __forceinline__ void stage_gather(const _Float16* __restrict__ pro_raw,
                                             const unsigned short* __restrict__ idxc,
                                             int tb, _Float16* dst, int w, int l) {
#pragma unroll
    for (int i = 0; i < 8; ++i) {
        const int off = w * 4096 + i * 512 + l * 8;   // elements, linear in l
        const int rowp = off >> 8;                    // w*16 + i*2 + (l>>5)
        const int m = idxc[tb + rowp];
        const int sc = (l & 31) ^ (rowp & 7);         // swizzled source chunk
        gload_lds16h(pro_raw + (size_t)m * 256 + (sc << 3), dst + off);
    }
}

// compute one compacted 128-row tile: wave owns rows w*16..w*16+15.
__device__ __forceinline__ void compute_tile(const _Float16* __restrict__ pb,
                                             const float* __restrict__ alfc,
                                             int tilebase, int NA,
                                             const f16x8 (&bfr)[4][8],
                                             int row, int ln7, int lq, int w,
                                             float (&Sa)[4], float (&Wa)[4]) {
    f32x4 acc[4];
#pragma unroll
    for (int p = 0; p < 4; ++p) acc[p] = (f32x4){0.f, 0.f, 0.f, 0.f};
#pragma unroll
    for (int ks = 0; ks < 8; ++ks) {
        const int ch = (ks * 4 + lq) ^ ln7;          // bank-correct swizzle
        const f16x8 a = *(const f16x8*)(pb + row * 256 + ch * 8);
#pragma unroll
        for (int p = 0; p < 4; ++p)
            acc[p] = __builtin_amdgcn_mfma_f32_16x16x32_f16(a, bfr[p][ks], acc[p], 0, 0, 0);
    }
    const int jb = tilebase + w * 16 + lq * 4;
    const f32x4 av = *(const f32x4*)(alfc + jb);
#pragma unroll
    for (int p = 0; p < 4; ++p) {
        float ssum = 0.f, wsum = 0.f;
#pragma unroll
        for (int r = 0; r < 4; ++r) {
            const float d = av[r] * acc[p][r];
            const float mk = (jb + r < NA) ? 1.f : 0.f;   // padding -> exactly 0
            const float e = mk * __expf(d - 20.f);
            ssum += e; wsum += e * d;
        }
        Sa[p] += ssum; Wa[p] += wsum;
    }
}

// K2: 256 blocks x 512 thr (8 waves, 1 block/CU). R11 per-wave pipeline over
// the COMPACTED proto list (ntiles = ceil(NA/128), data-dependent but
// deterministic).
__global__ __launch_bounds__(512, 2) void main_kernel(const float* __restrict__ qry,
                                                      const _Float16* __restrict__ pro_raw,
                                                      const float* __restrict__ psum,
                                                      const float* __restrict__ yv_ws,
                                                      float* __restrict__ out) {
    __shared__ __align__(16) _Float16 arena[65536];   // 128 KB
    __shared__ __align__(16) float alfc[1408];        // compacted alpha (pad 0)
    __shared__ unsigned short idxc[1408];             // compacted m (pad 0)
    __shared__ int tot_s[20];
    __shared__ float scr[1024];
    __shared__ float2 stats[64];
    __shared__ int iflags[2];

    float*     qtf  = (float*)arena;        // 64 KB [c][64px] (prologue)
    _Float16*  qs   = arena + 32768;        // bytes [64K,96K) (prologue)
    _Float16*  buf0 = arena;                // bytes [0,64K)   (main)
    _Float16*  buf1 = arena + 32768;        // bytes [64K,128K)(main)
    float*     red  = (float*)arena;        // 16 KB (epilogue, overlays buf0)

    const int t = threadIdx.x;
    const int w = t >> 6, l = t & 63;
    const int ln = l & 15, lq = l >> 4;
    const int ln7 = ln & 7;
    const int px0 = blockIdx.x * 64;

    if (t < 2) iflags[t] = 0;
    for (int i = t; i < 1408; i += 512) { alfc[i] = 0.f; idxc[i] = 0; }
    __syncthreads();

    // ---- issue qry staging (latency hidden by alpha/mask compute below) ----
#pragma unroll
    for (int i = 0; i < 8; ++i) {
        const int c = i * 32 + (t >> 4);
        gload_lds16f(qry + (size_t)c * 16384 + px0 + (t & 15) * 4,
                     qtf + i * 2048 + t * 4);
    }

    // ---- alpha[m] (registers) + mask flags (m = t, t+512, t+1024) ----
    float alf3[3], yv3[3];
    int f0 = 0, f1 = 0;
#pragma unroll
    for (int k = 0; k < 3; ++k) {
        const int m = t + k * 512;
        if (m < 1280) {
            float S1 = 0.f, S2 = 0.f;
            const f32x4* pp = (const f32x4*)(psum + m * 16);
#pragma unroll
            for (int u = 0; u < 4; ++u) {
                const f32x4 p = pp[u];
                S1 += p[0] + p[2]; S2 += p[1] + p[3];
            }
            alf3[k] = 20.f / fmaxf(sqrtf(fmaxf(S2 - S1 * S1 * (1.f / 256.f), 0.f)), 1e-4f);
            const float y = yv_ws[m];
            yv3[k] = y;
            if (y > 0.5f) f0 = 1;
            if (y > 0.1f) f1 = 1;
        }
    }
    if (f0) atomicOr(&iflags[0], 1);
    if (f1) atomicOr(&iflags[1], 1);
    __syncthreads();   // full drain: qtf ready, flags final, zeros visible

    // ---- ballot compaction counts (order-preserving over m) ----
    const int mode = iflags[0] ? 0 : (iflags[1] ? 1 : 2);
    int mk3[3] = {0, 0, 0}, pos3[3], chk3[3];
#pragma unroll
    for (int k = 0; k < 3; ++k) {
        const int m = t + k * 512;
        if (m < 1280) {   // wave-uniform guard
            const int mk = (mode == 0) ? (yv3[k] > 0.5f) : (mode == 1) ? (yv3[k] > 0.1f) : 1;
            mk3[k] = mk;
            const unsigned long long bal = __ballot(mk);
            pos3[k] = (int)__popcll(bal & ((1ull << l) - 1ull));
            chk3[k] = k * 8 + w;
            if (l == 0) tot_s[k * 8 + w] = (int)__popcll(bal);
        }
    }

    // ---- qnorm partials ----
    {
        const int p = t & 63, q = t >> 6;
        float s1 = 0.f, s2 = 0.f;
        for (int cc = 0; cc < 32; ++cc) {
            const float x = qtf[(q * 32 + cc) * 64 + p];
            s1 += x; s2 += x * x;
        }
        scr[q * 64 + p] = s1; scr[512 + q * 64 + p] = s2;
    }
    __syncthreads();   // scr + tot_s ready
    if (t < 64) {
        float S1 = 0.f, S2 = 0.f;
        for (int q = 0; q < 8; ++q) { S1 += scr[q * 64 + t]; S2 += scr[512 + q * 64 + t]; }
        const float mu = S1 * (1.f / 256.f);
        const float nrm = sqrtf(fmaxf(S2 - 256.f * mu * mu, 0.f));
        stats[t] = make_float2(mu, 1.f / fmaxf(nrm, 1e-4f));
    }
    // ---- prefix over 20 chunks (uniform) + scatter ----
    int NA;
    {
        int run = 0, base3[3] = {0, 0, 0};
#pragma unroll
        for (int c = 0; c < 20; ++c) {
#pragma unroll
            for (int k = 0; k < 3; ++k) if (c == k * 8 + w) base3[k] = run;
            run += tot_s[c];
        }
        NA = run;
#pragma unroll
        for (int k = 0; k < 3; ++k) {
            if (mk3[k]) {
                const int j = base3[k] + pos3[k];
                idxc[j] = (unsigned short)(t + k * 512);
                alfc[j] = alf3[k];
            }
        }
    }
    __syncthreads();   // stats + idxc/alfc ready
    {   // qs write (swizzled f16)
        const int px = t & 63, e = t >> 6;
        const float2 st = stats[px];
#pragma unroll
        for (int u = 0; u < 4; ++u) {
            const int g = e * 4 + u;
            f16x8 hv;
#pragma unroll
            for (int j = 0; j < 8; ++j)
                hv[j] = (_Float16)((qtf[(g * 8 + j) * 64 + px] - st.x) * st.y);
            *(f16x8*)(qs + px * 256 + ((g ^ (px & 7)) << 3)) = hv;
        }
    }
    __syncthreads();   // qs ready; qtf dead -> buf0 region free

    const int ntiles = (NA + 127) >> 7;

    stage_gather(pro_raw, idxc, 0, buf0, w, l);   // overlaps bfr hoist

    f16x8 bfr[4][8];
#pragma unroll
    for (int p = 0; p < 4; ++p) {
        const int px = p * 16 + ln;
        const int sB = px & 7;
#pragma unroll
        for (int ks = 0; ks < 8; ++ks) {
            const int g = ks * 4 + lq;
            bfr[p][ks] = *(const f16x8*)(qs + px * 256 + ((g ^ sB) << 3));
        }
    }
    __syncthreads();   // all waves done reading qs -> buf1 region free

    stage_gather(pro_raw, idxc, 128, buf1, w, l);

    const int row = w * 16 + ln;
    float Sa[4] = {0.f, 0.f, 0.f, 0.f}, Wa[4] = {0.f, 0.f, 0.f, 0.f};

#pragma unroll 1
    for (int tile = 0; tile < ntiles; ++tile) {
        if (tile < ntiles - 2) asm volatile("s_waitcnt vmcnt(8)" ::: "memory");
        else                   asm volatile("s_waitcnt vmcnt(0)" ::: "memory");
        compute_tile((tile & 1) ? buf1 : buf0, alfc, tile * 128, NA,
                     bfr, row, ln7, lq, w, Sa, Wa);
        if (tile + 2 < ntiles) {
            // all ds_reads of this buffer retired before we overwrite it
            asm volatile("s_waitcnt lgkmcnt(0)" ::: "memory");
            __builtin_amdgcn_sched_barrier(0);
            stage_gather(pro_raw, idxc, (tile + 2) * 128, (tile & 1) ? buf1 : buf0, w, l);
        }
    }

    __syncthreads();   // all waves done with buffers -> red overlay safe
#pragma unroll
    for (int p = 0; p < 4; ++p) {
        const int px = p * 16 + ln;
        const int slot = (w * 4 + lq + px) & 31;
        red[px * 32 + slot] = Sa[p];
        red[2048 + px * 32 + slot] = Wa[p];
    }
    __syncthreads();
    if (t < 64) {
        float S = 0.f, W = 0.f;
        for (int s = 0; s < 32; ++s) {
            const int slot = (s + t) & 31;
            S += red[t * 32 + slot];
            W += red[2048 + t * 32 + slot];
        }
        out[px0 + t] = W / S;
    }
}

extern "C" void kernel_launch(void* const* d_in, const int* in_sizes, int n_in,
                              void* d_out, int out_size, void* d_ws, size_t ws_size,
                              hipStream_t stream) {
    const float* qry   = (const float*)d_in[0];   // 256*16384
    const float* sup_x = (const float*)d_in[1];   // 5*256*16384
    const float* sup_y = (const float*)d_in[2];   // 5*16384
    float* out = (float*)d_out;                   // 16384

    char* ws = (char*)d_ws;
    _Float16*  pro_raw = (_Float16*)ws;           ws += 1280 * 256 * 2;   // 640 KB
    float*     psum    = (float*)ws;              ws += 1280 * 16 * 4;    // 80 KB
    float*     yv_ws   = (float*)ws;              /* 5 KB */

    pool_kernel<<<645, 256, 0, stream>>>(sup_x, sup_y, pro_raw, psum, yv_ws);
    main_kernel<<<256, 512, 0, stream>>>(qry, pro_raw, psum, yv_ws, out);
}